// Round 1
// baseline (505.388 us; speedup 1.0000x reference)
//
#include <hip/hip_runtime.h>
#include <hip/hip_bf16.h>
#include <math.h>

// Problem: B=16, N=1024, D=1024, H=8, HD=128
#define BN 1024
#define DD 1024
#define NB 16
#define NH 8
#define HDIM 128

typedef __attribute__((ext_vector_type(8))) short bf16x8;
typedef __attribute__((ext_vector_type(4))) float f32x4;
typedef __attribute__((ext_vector_type(4))) unsigned short ushort4v;

#define DEV __device__ __forceinline__

DEV unsigned short f2bf(float f) {
  unsigned u = __float_as_uint(f);
  u = (u + 0x7fffu + ((u >> 16) & 1u)) >> 16;  // RNE
  return (unsigned short)u;
}

DEV f32x4 mfma16(bf16x8 a, bf16x8 b, f32x4 c) {
  return __builtin_amdgcn_mfma_f32_16x16x32_bf16(a, b, c, 0, 0, 0);
}

// ---------------------------------------------------------------------------
// K0: x fp32 -> bf16, vectorized
// ---------------------------------------------------------------------------
__global__ __launch_bounds__(256) void conv_x_kernel(const float* __restrict__ in,
                                                     unsigned short* __restrict__ out) {
  int i = blockIdx.x * 256 + threadIdx.x;  // element-quad index
  const float4* p = (const float4*)in;
  float4 v = p[i];
  ushort4v o;
  o[0] = f2bf(v.x); o[1] = f2bf(v.y); o[2] = f2bf(v.z); o[3] = f2bf(v.w);
  *(ushort4v*)(out + (size_t)i * 4) = o;
}

// ---------------------------------------------------------------------------
// K1: Wq/Wk/Wv [H,D,HD] fp32 -> wqkvT [3*D][D] bf16 where row c=(which*1024+h*128+e),
//     col k=d : wqkvT[c][k] = W_which[h][k][e]. (32x32 LDS tile transpose)
// grid (32, 4, 24) block (32, 8)
// ---------------------------------------------------------------------------
__global__ __launch_bounds__(256) void transpose_qkv_kernel(const float* __restrict__ Wq,
                                                            const float* __restrict__ Wk,
                                                            const float* __restrict__ Wv,
                                                            unsigned short* __restrict__ outT) {
  __shared__ float tile[32][33];
  int z = blockIdx.z;
  int which = z >> 3, h = z & 7;
  const float* in = (which == 0 ? Wq : (which == 1 ? Wk : Wv)) + (size_t)h * DD * HDIM;
  int k0 = blockIdx.x * 32, e0 = blockIdx.y * 32;
  int tx = threadIdx.x, ty = threadIdx.y;
#pragma unroll
  for (int i = 0; i < 4; ++i)
    tile[ty + i * 8][tx] = in[(size_t)(k0 + ty + i * 8) * HDIM + e0 + tx];
  __syncthreads();
  int rowbase = which * 1024 + h * 128 + e0;
#pragma unroll
  for (int i = 0; i < 4; ++i)
    outT[(size_t)(rowbase + ty + i * 8) * DD + k0 + tx] = f2bf(tile[tx][ty + i * 8]);
}

// ---------------------------------------------------------------------------
// K2: Wfc [D][D] -> wfcT [c][d] bf16.  grid (32,32) block (32,8)
// ---------------------------------------------------------------------------
__global__ __launch_bounds__(256) void transpose_fc_kernel(const float* __restrict__ W,
                                                           unsigned short* __restrict__ outT) {
  __shared__ float tile[32][33];
  int d0 = blockIdx.x * 32, c0 = blockIdx.y * 32;
  int tx = threadIdx.x, ty = threadIdx.y;
#pragma unroll
  for (int i = 0; i < 4; ++i)
    tile[ty + i * 8][tx] = W[(size_t)(d0 + ty + i * 8) * DD + c0 + tx];
  __syncthreads();
#pragma unroll
  for (int i = 0; i < 4; ++i)
    outT[(size_t)(c0 + ty + i * 8) * DD + d0 + tx] = f2bf(tile[tx][ty + i * 8]);
}

// ---------------------------------------------------------------------------
// GEMM: C[M=16384][Nc] = A[m][k] * Bt[n][k]^T, bf16 MFMA 16x16x32, fp32 accum.
// 128x128 block tile, BK=32, 4 waves in 2x2 (64x64 per wave).
// MODE 0: Nc=3072 (qkv). Writes q/k as [B,H,N,HD] bf16, v transposed [B,H,HD,N].
// MODE 1: Nc=1024 (fc).  Writes fp32 out + bias.
// LDS: A/B tiles [128][32] padded to stride 40 (bank-safe: 80B rows -> 2-way=free).
// ---------------------------------------------------------------------------
#define LDSK 40

template <int MODE>
__global__ __launch_bounds__(256, 3) void gemm128_kernel(
    const unsigned short* __restrict__ A, const unsigned short* __restrict__ Bt,
    const float* __restrict__ bias0, const float* __restrict__ bias1,
    const float* __restrict__ bias2, unsigned short* __restrict__ out0,
    unsigned short* __restrict__ out1, unsigned short* __restrict__ out2,
    float* __restrict__ outf) {
  __shared__ unsigned short as[128 * LDSK];
  __shared__ unsigned short bs[128 * LDSK];
  const int tid = threadIdx.x;
  const int wave = tid >> 6, lane = tid & 63, quad = lane >> 4, l15 = lane & 15;
  const int wr = wave >> 1, wc = wave & 1;
  const int m0 = blockIdx.y * 128, n0 = blockIdx.x * 128;
  const int K = 1024;
  f32x4 acc[4][4] = {};
  const int sr = tid >> 2;        // 0..63
  const int sc = (tid & 3) * 8;   // 0,8,16,24

  for (int kb = 0; kb < K; kb += 32) {
#pragma unroll
    for (int half = 0; half < 2; ++half) {
      int r = sr + half * 64;
      bf16x8 av = *(const bf16x8*)(A + (size_t)(m0 + r) * K + kb + sc);
      *(bf16x8*)(as + r * LDSK + sc) = av;
      bf16x8 bv8 = *(const bf16x8*)(Bt + (size_t)(n0 + r) * K + kb + sc);
      *(bf16x8*)(bs + r * LDSK + sc) = bv8;
    }
    __syncthreads();
    bf16x8 af[4], bfr[4];
#pragma unroll
    for (int mt = 0; mt < 4; ++mt)
      af[mt] = *(const bf16x8*)(as + (wr * 64 + mt * 16 + l15) * LDSK + quad * 8);
#pragma unroll
    for (int nt = 0; nt < 4; ++nt)
      bfr[nt] = *(const bf16x8*)(bs + (wc * 64 + nt * 16 + l15) * LDSK + quad * 8);
#pragma unroll
    for (int mt = 0; mt < 4; ++mt)
#pragma unroll
      for (int nt = 0; nt < 4; ++nt)
        acc[mt][nt] = mfma16(af[mt], bfr[nt], acc[mt][nt]);
    __syncthreads();
  }

  if constexpr (MODE == 0) {
    const int seg = n0 >> 10;  // 0=q 1=k 2=v (block col range never crosses a segment)
#pragma unroll
    for (int mt = 0; mt < 4; ++mt) {
      int mb = m0 + wr * 64 + mt * 16 + quad * 4;
      int bb = mb >> 10, nn = mb & 1023;
#pragma unroll
      for (int nt = 0; nt < 4; ++nt) {
        int c = n0 + wc * 64 + nt * 16 + l15;
        int cc = c & 1023;
        int h = cc >> 7, e = cc & 127;
        if (seg == 2) {
          float bias = bias2[cc];
          ushort4v pv;
#pragma unroll
          for (int r = 0; r < 4; ++r) pv[r] = f2bf(acc[mt][nt][r] + bias);
          // vT layout [b][h][e][n]; 4 regs = 4 consecutive n -> packed 8B store
          *(ushort4v*)(out2 + ((size_t)(bb * NH + h) * HDIM + e) * BN + nn) = pv;
        } else {
          const float* bp = (seg == 0) ? bias0 : bias1;
          unsigned short* op = (seg == 0) ? out0 : out1;
          float bias = bp[cc];
#pragma unroll
          for (int r = 0; r < 4; ++r)
            op[(((size_t)bb * NH + h) * BN + (nn + r)) * HDIM + e] =
                f2bf(acc[mt][nt][r] + bias);
        }
      }
    }
  } else {
#pragma unroll
    for (int mt = 0; mt < 4; ++mt) {
      int mb = m0 + wr * 64 + mt * 16 + quad * 4;
#pragma unroll
      for (int nt = 0; nt < 4; ++nt) {
        int c = n0 + wc * 64 + nt * 16 + l15;
        float bias = bias0[c];
#pragma unroll
        for (int r = 0; r < 4; ++r)
          outf[(size_t)(mb + r) * DD + c] = acc[mt][nt][r] + bias;
      }
    }
  }
}

// ---------------------------------------------------------------------------
// K4: flash attention. One block = (bh, 128-query tile). 4 waves, wave = 32 rows.
// BK=64 keys/iter. Q A-frags in registers. K,V staged in LDS; V comes in
// pre-transposed [B,H,HD,N] so its LDS tile is directly B-operand friendly.
// Exact reference mask semantics: masked -> -1e30; fully-masked query row ->
// uniform softmax (falls out of online-softmax identities).
// ---------------------------------------------------------------------------
__global__ __launch_bounds__(256, 2) void flash_attn_kernel(
    const unsigned short* __restrict__ Q, const unsigned short* __restrict__ Kk,
    const unsigned short* __restrict__ Vt, const int* __restrict__ xmask,
    unsigned short* __restrict__ O) {
  __shared__ unsigned short k_s[64 * 136];      // [key][hd], pad 136
  __shared__ unsigned short v_s[128 * 72];      // [e][key], pad 72
  __shared__ unsigned short p_s[4][32 * 72];    // per-wave P scratch [row][key]
  __shared__ int km_s[64];

  const float SCALE = 0.08838834764831845f;  // 1/sqrt(128)
  const float NEGV = -1e30f;

  const int tid = threadIdx.x;
  const int w = tid >> 6, lane = tid & 63, quad = lane >> 4, l15 = lane & 15;
  const int qb = blockIdx.x, bh = blockIdx.y;
  const int b = bh >> 3, h = bh & 7;
  const int q0 = qb * 128;
  const unsigned short* qp = Q + ((size_t)bh * BN + q0) * HDIM;
  const unsigned short* kp = Kk + (size_t)bh * BN * HDIM;
  const unsigned short* vp = Vt + (size_t)bh * HDIM * BN;

  // Q fragments (A-layout): row = w*32 + mt*16 + l15, k = ks*32 + quad*8 + j
  bf16x8 qf[2][4];
#pragma unroll
  for (int mt = 0; mt < 2; ++mt)
#pragma unroll
    for (int ks = 0; ks < 4; ++ks)
      qf[mt][ks] = *(const bf16x8*)(qp + (w * 32 + mt * 16 + l15) * HDIM + ks * 32 + quad * 8);

  // row masks for this lane's rows (C-layout rows: quad*4 + r)
  int rowm[2][4];
#pragma unroll
  for (int mt = 0; mt < 2; ++mt)
#pragma unroll
    for (int r = 0; r < 4; ++r)
      rowm[mt][r] = xmask[b * BN + q0 + w * 32 + mt * 16 + quad * 4 + r];

  float m_run[2][4], l_run[2][4];
#pragma unroll
  for (int mt = 0; mt < 2; ++mt)
#pragma unroll
    for (int r = 0; r < 4; ++r) { m_run[mt][r] = -3.0e38f; l_run[mt][r] = 0.0f; }
  f32x4 o_acc[2][8] = {};

  for (int kb = 0; kb < BN; kb += 64) {
    // stage K tile: 64 rows x 128 hd
#pragma unroll
    for (int it = 0; it < 4; ++it) {
      int c = it * 256 + tid;
      int row = c >> 4, off = (c & 15) * 8;
      *(bf16x8*)(k_s + row * 136 + off) = *(const bf16x8*)(kp + (size_t)(kb + row) * HDIM + off);
    }
    // stage V tile: 128 e-rows x 64 keys (from transposed V)
#pragma unroll
    for (int it = 0; it < 4; ++it) {
      int c = it * 256 + tid;
      int row = c >> 3, off = (c & 7) * 8;
      *(bf16x8*)(v_s + row * 72 + off) = *(const bf16x8*)(vp + (size_t)row * BN + kb + off);
    }
    if (tid < 64) km_s[tid] = xmask[b * BN + kb + tid];
    __syncthreads();

    // S = Q K^T  (wave strip: 32 rows x 64 keys)
    f32x4 s[2][4] = {};
#pragma unroll
    for (int ks = 0; ks < 4; ++ks) {
      bf16x8 bfr[4];
#pragma unroll
      for (int nt = 0; nt < 4; ++nt)
        bfr[nt] = *(const bf16x8*)(k_s + (nt * 16 + l15) * 136 + ks * 32 + quad * 8);
#pragma unroll
      for (int mt = 0; mt < 2; ++mt)
#pragma unroll
        for (int nt = 0; nt < 4; ++nt)
          s[mt][nt] = mfma16(qf[mt][ks], bfr[nt], s[mt][nt]);
    }

    // mask + online softmax
    int cm[4];
#pragma unroll
    for (int nt = 0; nt < 4; ++nt) cm[nt] = km_s[nt * 16 + l15];
#pragma unroll
    for (int mt = 0; mt < 2; ++mt) {
#pragma unroll
      for (int r = 0; r < 4; ++r) {
        float sv[4];
#pragma unroll
        for (int nt = 0; nt < 4; ++nt) {
          float x = s[mt][nt][r];
          sv[nt] = (rowm[mt][r] && cm[nt]) ? x * SCALE : NEGV;
        }
        float rmax = fmaxf(fmaxf(sv[0], sv[1]), fmaxf(sv[2], sv[3]));
#pragma unroll
        for (int off = 1; off < 16; off <<= 1)
          rmax = fmaxf(rmax, __shfl_xor(rmax, off, 64));
        float mn = fmaxf(m_run[mt][r], rmax);
        float alpha = __expf(m_run[mt][r] - mn);
        float rsum = 0.0f;
#pragma unroll
        for (int nt = 0; nt < 4; ++nt) {
          float p = __expf(sv[nt] - mn);
          rsum += p;
          p_s[w][(mt * 16 + quad * 4 + r) * 72 + nt * 16 + l15] = f2bf(p);
        }
#pragma unroll
        for (int off = 1; off < 16; off <<= 1) rsum += __shfl_xor(rsum, off, 64);
        l_run[mt][r] = l_run[mt][r] * alpha + rsum;
        m_run[mt][r] = mn;
#pragma unroll
        for (int et = 0; et < 8; ++et) o_acc[mt][et][r] *= alpha;
      }
    }

    // O += P V  (P via per-wave LDS round-trip into A-layout)
#pragma unroll
    for (int ks2 = 0; ks2 < 2; ++ks2) {
      bf16x8 pa[2];
#pragma unroll
      for (int mt = 0; mt < 2; ++mt)
        pa[mt] = *(const bf16x8*)(p_s[w] + (mt * 16 + l15) * 72 + ks2 * 32 + quad * 8);
#pragma unroll
      for (int et = 0; et < 8; ++et) {
        bf16x8 bv = *(const bf16x8*)(v_s + (et * 16 + l15) * 72 + ks2 * 32 + quad * 8);
#pragma unroll
        for (int mt = 0; mt < 2; ++mt)
          o_acc[mt][et] = mfma16(pa[mt], bv, o_acc[mt][et]);
      }
    }
    __syncthreads();
  }

  // epilogue: O/l, store as o_bf[b*N + row][h*128 + e]
#pragma unroll
  for (int mt = 0; mt < 2; ++mt)
#pragma unroll
    for (int r = 0; r < 4; ++r) {
      float inv = 1.0f / l_run[mt][r];
      int row = q0 + w * 32 + mt * 16 + quad * 4 + r;
#pragma unroll
      for (int et = 0; et < 8; ++et) {
        int col = h * HDIM + et * 16 + l15;
        O[((size_t)b * BN + row) * DD + col] = f2bf(o_acc[mt][et][r] * inv);
      }
    }
}

// ---------------------------------------------------------------------------
// Workspace layout (bytes):  total 176,160,768 (~168 MB)
//   x_bf    @ 0          33,554,432
//   wqkvT   @ 33554432    6,291,456
//   wfcT    @ 39845888    2,097,152
//   q_bf    @ 41943040   33,554,432
//   k_bf    @ 75497472   33,554,432
//   vT_bf   @ 109051904  33,554,432
//   o_bf    @ 142606336  33,554,432
// ---------------------------------------------------------------------------
extern "C" void kernel_launch(void* const* d_in, const int* in_sizes, int n_in,
                              void* d_out, int out_size, void* d_ws, size_t ws_size,
                              hipStream_t stream) {
  const float* x = (const float*)d_in[0];
  const int* xmask = (const int*)d_in[1];
  const float* Wq = (const float*)d_in[2];
  const float* bq = (const float*)d_in[3];
  const float* Wk = (const float*)d_in[4];
  const float* bk = (const float*)d_in[5];
  const float* Wv = (const float*)d_in[6];
  const float* bv = (const float*)d_in[7];
  const float* Wfc = (const float*)d_in[8];
  const float* bfc = (const float*)d_in[9];
  float* out = (float*)d_out;

  char* ws = (char*)d_ws;
  unsigned short* x_bf  = (unsigned short*)(ws);
  unsigned short* wqkvT = (unsigned short*)(ws + 33554432);
  unsigned short* wfcT  = (unsigned short*)(ws + 39845888);
  unsigned short* q_bf  = (unsigned short*)(ws + 41943040);
  unsigned short* k_bf  = (unsigned short*)(ws + 75497472);
  unsigned short* vT_bf = (unsigned short*)(ws + 109051904);
  unsigned short* o_bf  = (unsigned short*)(ws + 142606336);

  conv_x_kernel<<<dim3(16384), dim3(256), 0, stream>>>(x, x_bf);
  transpose_qkv_kernel<<<dim3(32, 4, 24), dim3(32, 8), 0, stream>>>(Wq, Wk, Wv, wqkvT);
  transpose_fc_kernel<<<dim3(32, 32), dim3(32, 8), 0, stream>>>(Wfc, wfcT);

  // QKV projection: M=16384, Nc=3072, K=1024
  gemm128_kernel<0><<<dim3(24, 128), dim3(256), 0, stream>>>(
      x_bf, wqkvT, bq, bk, bv, q_bf, k_bf, vT_bf, nullptr);

  // attention: grid (qblocks=8, bh=128)
  flash_attn_kernel<<<dim3(8, 128), dim3(256), 0, stream>>>(q_bf, k_bf, vT_bf, xmask, o_bf);

  // output FC: M=16384, Nc=1024, K=1024
  gemm128_kernel<1><<<dim3(8, 128), dim3(256), 0, stream>>>(
      o_bf, wfcT, bfc, nullptr, nullptr, nullptr, nullptr, nullptr, out);
}